// Round 6
// baseline (965.168 us; speedup 1.0000x reference)
//
#include <hip/hip_runtime.h>

typedef __bf16 bf16;
typedef __attribute__((ext_vector_type(8))) __bf16 bf16x8;
typedef __attribute__((ext_vector_type(4))) float f32x4;
typedef __attribute__((ext_vector_type(4))) unsigned int u32x4;

#define MFMA16(a, b, c) __builtin_amdgcn_mfma_f32_16x16x32_bf16(a, b, c, 0, 0, 0)

#define C_DIM 1024
#define N_TOK 4096
#define BATCH 4
#define HEADS 16
#define HD 64
#define BS 64
#define NB 64
#define M_TOT (BATCH * N_TOK)              // 16384
#define QKV_ELEMS ((size_t)M_TOT * C_DIM)  // 16777216 elems per tensor

// ---------------------------------------------------------------------------
// Dtype detector (robustness): f32 inputs -> bits7..14 are mantissa (~16% in
// [100,140]); bf16-pair inputs -> low-half exponent (~100% in range).
// flag = 0 -> bf16 inputs ; flag = 1 -> f32 inputs.
// ---------------------------------------------------------------------------
__global__ void detect_kernel(const unsigned int* __restrict__ x, int* flag) {
    if (threadIdx.x == 0) {
        int cnt = 0;
        for (int i = 0; i < 256; ++i) {
            unsigned int e = (x[i] >> 7) & 0xFFu;
            cnt += (e >= 100u && e <= 140u) ? 1 : 0;
        }
        *flag = (cnt >= 192) ? 0 : 1;
    }
}

// Diagnostic: fill f32 output with a constant (absmax becomes ~val).
__global__ void sentinel_kernel(float* out, float val, int n) {
    int i = blockIdx.x * 256 + threadIdx.x;
    if (i < n) out[i] = val;
}

__device__ __forceinline__ bf16x8 cvt8(f32x4 a, f32x4 b) {
    bf16x8 r;
    r[0] = (bf16)a[0]; r[1] = (bf16)a[1]; r[2] = (bf16)a[2]; r[3] = (bf16)a[3];
    r[4] = (bf16)b[0]; r[5] = (bf16)b[1]; r[6] = (bf16)b[2]; r[7] = (bf16)b[3];
    return r;
}

__device__ __forceinline__ float rd1(const void* p, int i, int isf) {
    return isf ? ((const float*)p)[i] : (float)((const bf16*)p)[i];
}

// Stage a 128x64 tile (element offset eoff, leading dim ld) into LDS as bf16.
__device__ __forceinline__ void stage128(const void* g, size_t eoff, int ld,
                                         bf16* l, int tid, int isf) {
#pragma unroll
    for (int p = 0; p < 4; ++p) {
        const int e = (p * 256 + tid) * 8;
        const int row = e >> 6, col = e & 63;
        const size_t o = eoff + (size_t)row * ld + col;
        if (isf) {
            const float* gp = (const float*)g + o;
            *(bf16x8*)(l + e) = cvt8(*(const f32x4*)gp, *(const f32x4*)(gp + 4));
        } else {
            *(u32x4*)(l + e) = *(const u32x4*)((const bf16*)g + o);
        }
    }
}

// Stage a 64x64 bf16 tile from flat layout (rows grow0.., cols colbase..+63).
__device__ __forceinline__ void stage_head(const bf16* g, int grow0, int colbase,
                                           bf16* l, int tid, bool zero) {
#pragma unroll
    for (int p = 0; p < 2; ++p) {
        const int e = (p * 256 + tid) * 8;
        const int row = e >> 6, col = e & 63;
        if (zero) {
            u32x4 z = {};
            *(u32x4*)(l + e) = z;
        } else {
            *(u32x4*)(l + e) =
                *(const u32x4*)(g + (size_t)(grow0 + row) * C_DIM + colbase + col);
        }
    }
}

// ---------------------------------------------------------------------------
// Kernel 1: fused QKV projection, flat [16384,1024] bf16 outputs.
// ---------------------------------------------------------------------------
__global__ __launch_bounds__(256) void qkv_kernel(
    const void* __restrict__ x,
    const void* __restrict__ Wq, const void* __restrict__ bq,
    const void* __restrict__ Wk, const void* __restrict__ bk,
    const void* __restrict__ Wv, const void* __restrict__ bv,
    bf16* __restrict__ qo, bf16* __restrict__ ko, bf16* __restrict__ vo,
    const int* __restrict__ flag)
{
    __shared__ __align__(16) bf16 As[128 * 64];
    __shared__ __align__(16) bf16 Bs[128 * 64];

    const int isf = *flag;
    const int which = blockIdx.z;
    const void* W   = which == 0 ? Wq : (which == 1 ? Wk : Wv);
    const void* bia = which == 0 ? bq : (which == 1 ? bk : bv);
    bf16* dst       = which == 0 ? qo : (which == 1 ? ko : vo);

    const int m0 = blockIdx.x * 128;
    const int c0 = blockIdx.y * 128;
    const int tid = threadIdx.x;
    const int w = tid >> 6, lane = tid & 63;
    const int wr = w >> 1, wc = w & 1;
    const int lr = lane & 15, quad = lane >> 4;

    f32x4 acc[4][4] = {};

    for (int kt = 0; kt < 16; ++kt) {
        const int k0 = kt * 64;
        stage128(x, (size_t)m0 * C_DIM + k0, C_DIM, As, tid, isf);
        stage128(W, (size_t)c0 * C_DIM + k0, C_DIM, Bs, tid, isf);
        __syncthreads();
#pragma unroll
        for (int ks = 0; ks < 2; ++ks) {
            bf16x8 af[4], bfr[4];
#pragma unroll
            for (int mi = 0; mi < 4; ++mi)
                af[mi] = *(const bf16x8*)(As + (wr * 64 + mi * 16 + lr) * 64 + ks * 32 + quad * 8);
#pragma unroll
            for (int ni = 0; ni < 4; ++ni)
                bfr[ni] = *(const bf16x8*)(Bs + (wc * 64 + ni * 16 + lr) * 64 + ks * 32 + quad * 8);
#pragma unroll
            for (int mi = 0; mi < 4; ++mi)
#pragma unroll
                for (int ni = 0; ni < 4; ++ni)
                    acc[mi][ni] = MFMA16(af[mi], bfr[ni], acc[mi][ni]);
        }
        __syncthreads();
    }

#pragma unroll
    for (int ni = 0; ni < 4; ++ni) {
        const int c = c0 + wc * 64 + ni * 16 + lr;
        const float bv_ = rd1(bia, c, isf);
#pragma unroll
        for (int mi = 0; mi < 4; ++mi) {
#pragma unroll
            for (int r = 0; r < 4; ++r) {
                const int m = m0 + wr * 64 + mi * 16 + quad * 4 + r;
                dst[(size_t)m * C_DIM + c] = (bf16)(acc[mi][ni][r] + bv_);
            }
        }
    }
}

// ---------------------------------------------------------------------------
// Kernel 2: block-sparse attention, scalar online-softmax, flat bf16 q/k/v.
// One wg per (nblk, bh); tid>>2 = query row, tid&3 = 16-wide slice.
// O overwrites q's (block,head) slice in place (sole reader = this wg).
// ---------------------------------------------------------------------------
__global__ __launch_bounds__(256) void attn_kernel(
    const bf16* qg, const bf16* __restrict__ kg,
    const bf16* __restrict__ vg, bf16* ob)
{
    __shared__ __align__(16) bf16 Qs[4096];
    __shared__ __align__(16) bf16 Ks[4096];
    __shared__ __align__(16) bf16 Vs[4096];
    __shared__ __align__(16) bf16 Ps[4096];

    const int nblk = blockIdx.x, bh = blockIdx.y, tid = threadIdx.x;
    const int b = bh >> 4, h = bh & 15;
    const int qi = tid >> 2, l4 = tid & 3;
    const int grow = b * N_TOK + nblk * BS;
    const int colbase = h * HD;

    stage_head(qg, grow, colbase, Qs, tid, false);
    __syncthreads();

    float qv[64];
#pragma unroll
    for (int d8 = 0; d8 < 8; ++d8) {
        bf16x8 q8 = *(const bf16x8*)(Qs + qi * 64 + d8 * 8);
#pragma unroll
        for (int j = 0; j < 8; ++j) qv[d8 * 8 + j] = (float)q8[j];
    }

    float m_ = -3e38f, l_ = 0.f, O[16] = {};

    for (int wb = 0; wb < 3; ++wb) {
        const int gb = nblk - 1 + wb;
        const bool ok = (gb >= 0 && gb < NB);
        __syncthreads();
        stage_head(kg, b * N_TOK + gb * BS, colbase, Ks, tid, !ok);
        stage_head(vg, b * N_TOK + gb * BS, colbase, Vs, tid, !ok);
        __syncthreads();

        float sv[16];
        float mb = -3e38f;
#pragma unroll
        for (int jj = 0; jj < 16; ++jj) {
            const int k = l4 * 16 + jj;
            const int jwin = wb * 64 + k;
            float a;
            if (ok && (64 + qi >= jwin)) {
                a = 0.f;
#pragma unroll
                for (int d8 = 0; d8 < 8; ++d8) {
                    bf16x8 kv = *(const bf16x8*)(Ks + k * 64 + d8 * 8);
#pragma unroll
                    for (int j = 0; j < 8; ++j) a += qv[d8 * 8 + j] * (float)kv[j];
                }
                a *= 0.125f;
            } else {
                a = -3e38f;
            }
            sv[jj] = a;
            mb = fmaxf(mb, a);
        }
        mb = fmaxf(mb, __shfl_xor(mb, 1));
        mb = fmaxf(mb, __shfl_xor(mb, 2));
        const float mn = fmaxf(m_, mb);
        const float alpha = __expf(m_ - mn);

        float ls = 0.f;
#pragma unroll
        for (int jj = 0; jj < 16; ++jj) {
            const float p = (sv[jj] > -1e37f) ? __expf(sv[jj] - mn) : 0.f;
            Ps[qi * 64 + l4 * 16 + jj] = (bf16)p;
            ls += p;
        }
        ls += __shfl_xor(ls, 1);
        ls += __shfl_xor(ls, 2);
        l_ = l_ * alpha + ls;
        m_ = mn;
#pragma unroll
        for (int j = 0; j < 16; ++j) O[j] *= alpha;
        __syncthreads();

        for (int k = 0; k < 64; ++k) {
            const float p = (float)Ps[qi * 64 + k];
            bf16x8 v0 = *(const bf16x8*)(Vs + k * 64 + l4 * 16);
            bf16x8 v1 = *(const bf16x8*)(Vs + k * 64 + l4 * 16 + 8);
#pragma unroll
            for (int j = 0; j < 8; ++j) O[j]     += p * (float)v0[j];
#pragma unroll
            for (int j = 0; j < 8; ++j) O[8 + j] += p * (float)v1[j];
        }
    }

    const float inv = 1.f / l_;
#pragma unroll
    for (int j = 0; j < 16; ++j)
        ob[(size_t)(grow + qi) * C_DIM + colbase + l4 * 16 + j] = (bf16)(O[j] * inv);
}

// ---------------------------------------------------------------------------
// Kernel 3: output projection -> FLOAT32 output (the reference's out dtype).
// ---------------------------------------------------------------------------
__global__ __launch_bounds__(256) void outproj_kernel(
    const bf16* __restrict__ o, const void* __restrict__ Wo,
    const void* __restrict__ bo, float* __restrict__ out,
    const int* __restrict__ flag)
{
    __shared__ __align__(16) bf16 As[128 * 64];
    __shared__ __align__(16) bf16 Bs[128 * 64];

    const int isf = *flag;
    const int m0 = blockIdx.x * 128;
    const int c0 = blockIdx.y * 128;
    const int tid = threadIdx.x;
    const int w = tid >> 6, lane = tid & 63;
    const int wr = w >> 1, wc = w & 1;
    const int lr = lane & 15, quad = lane >> 4;

    f32x4 acc[4][4] = {};

    for (int kt = 0; kt < 16; ++kt) {
        const int k0 = kt * 64;
        stage128(o, (size_t)m0 * C_DIM + k0, C_DIM, As, tid, 0);
        stage128(Wo, (size_t)c0 * C_DIM + k0, C_DIM, Bs, tid, isf);
        __syncthreads();
#pragma unroll
        for (int ks = 0; ks < 2; ++ks) {
            bf16x8 af[4], bfr[4];
#pragma unroll
            for (int mi = 0; mi < 4; ++mi)
                af[mi] = *(const bf16x8*)(As + (wr * 64 + mi * 16 + lr) * 64 + ks * 32 + quad * 8);
#pragma unroll
            for (int ni = 0; ni < 4; ++ni)
                bfr[ni] = *(const bf16x8*)(Bs + (wc * 64 + ni * 16 + lr) * 64 + ks * 32 + quad * 8);
#pragma unroll
            for (int mi = 0; mi < 4; ++mi)
#pragma unroll
                for (int ni = 0; ni < 4; ++ni)
                    acc[mi][ni] = MFMA16(af[mi], bfr[ni], acc[mi][ni]);
        }
        __syncthreads();
    }

#pragma unroll
    for (int ni = 0; ni < 4; ++ni) {
        const int c = c0 + wc * 64 + ni * 16 + lr;
        const float bv_ = rd1(bo, c, isf);
#pragma unroll
        for (int mi = 0; mi < 4; ++mi) {
#pragma unroll
            for (int r = 0; r < 4; ++r) {
                const int m = m0 + wr * 64 + mi * 16 + quad * 4 + r;
                out[(size_t)m * C_DIM + c] = acc[mi][ni][r] + bv_;
            }
        }
    }
}

extern "C" void kernel_launch(void* const* d_in, const int* in_sizes, int n_in,
                              void* d_out, int out_size, void* d_ws, size_t ws_size,
                              hipStream_t stream) {
    const void* x  = d_in[0];
    const void* Wq = d_in[1];
    const void* bq = d_in[2];
    const void* Wk = d_in[3];
    const void* bk = d_in[4];
    const void* Wv = d_in[5];
    const void* bv = d_in[6];
    const void* Wo = d_in[7];
    const void* bo = d_in[8];
    float* out = (float*)d_out;

    const int sb = (out_size + 255) / 256;

    const bool sizes_ok = (n_in == 9) &&
        in_sizes[0] == (int)QKV_ELEMS &&
        in_sizes[1] == C_DIM * C_DIM && in_sizes[2] == C_DIM &&
        in_sizes[3] == C_DIM * C_DIM && in_sizes[4] == C_DIM &&
        in_sizes[5] == C_DIM * C_DIM && in_sizes[6] == C_DIM &&
        in_sizes[7] == C_DIM * C_DIM && in_sizes[8] == C_DIM &&
        out_size == (int)QKV_ELEMS;
    if (!sizes_ok) {
        sentinel_kernel<<<sb, 256, 0, stream>>>(out, 777.0f, out_size);
        return;
    }
    const size_t need = 4096 + 2 * (QKV_ELEMS * sizeof(bf16));   // q + k, 64 MB
    if (ws_size < need) {
        sentinel_kernel<<<sb, 256, 0, stream>>>(out, 999.0f, out_size);
        return;
    }

    int* flag = (int*)d_ws;
    bf16* q = (bf16*)((char*)d_ws + 4096);   // 32 MB, becomes attn O in place
    bf16* k = q + QKV_ELEMS;                 // 32 MB
    // v parks in d_out's upper 32 MB (d_out = 64 MB f32; v dead before the
    // f32 outproj store clobbers it — same-stream kernel ordering).
    bf16* v = (bf16*)((char*)d_out + QKV_ELEMS * sizeof(bf16));

    detect_kernel<<<1, 64, 0, stream>>>((const unsigned int*)x, flag);

    dim3 g1(M_TOT / 128, C_DIM / 128, 3);
    qkv_kernel<<<g1, 256, 0, stream>>>(x, Wq, bq, Wk, bk, Wv, bv, q, k, v, flag);

    attn_kernel<<<dim3(NB, BATCH * HEADS), 256, 0, stream>>>(q, k, v, q);

    dim3 g3(M_TOT / 128, C_DIM / 128);
    outproj_kernel<<<g3, 256, 0, stream>>>(q, Wo, bo, out, flag);
}

// Round 7
// 511.565 us; speedup vs baseline: 1.8867x; 1.8867x over previous
//
#include <hip/hip_runtime.h>

typedef __bf16 bf16;
typedef __attribute__((ext_vector_type(8))) __bf16 bf16x8;
typedef __attribute__((ext_vector_type(4))) float f32x4;
typedef __attribute__((ext_vector_type(4))) unsigned int u32x4;

#define MFMA16(a, b, c) __builtin_amdgcn_mfma_f32_16x16x32_bf16(a, b, c, 0, 0, 0)

#define C_DIM 1024
#define N_TOK 4096
#define BATCH 4
#define HEADS 16
#define HD 64
#define BS 64
#define NB 64
#define M_TOT (BATCH * N_TOK)              // 16384
#define QKV_ELEMS ((size_t)M_TOT * C_DIM)  // 16777216
#define W_ELEMS (C_DIM * C_DIM)            // 1048576
#define VT_LD 200                          // V^T row stride (16B-aligned, low-conflict)

// ---------------------------------------------------------------------------
// Dtype detector: flag=0 -> inputs bf16, flag=1 -> inputs f32.
// ---------------------------------------------------------------------------
__global__ void detect_kernel(const unsigned int* __restrict__ x, int* flag) {
    if (threadIdx.x == 0) {
        int cnt = 0;
        for (int i = 0; i < 256; ++i) {
            unsigned int e = (x[i] >> 7) & 0xFFu;
            cnt += (e >= 100u && e <= 140u) ? 1 : 0;
        }
        *flag = (cnt >= 192) ? 0 : 1;
    }
}

__global__ void sentinel_kernel(float* out, float val, int n) {
    int i = blockIdx.x * 256 + threadIdx.x;
    if (i < n) out[i] = val;
}

__device__ __forceinline__ bf16x8 cvt8(f32x4 a, f32x4 b) {
    bf16x8 r;
    r[0] = (bf16)a[0]; r[1] = (bf16)a[1]; r[2] = (bf16)a[2]; r[3] = (bf16)a[3];
    r[4] = (bf16)b[0]; r[5] = (bf16)b[1]; r[6] = (bf16)b[2]; r[7] = (bf16)b[3];
    return r;
}

__device__ __forceinline__ float rd1(const void* p, int i, int isf) {
    return isf ? ((const float*)p)[i] : (float)((const bf16*)p)[i];
}

// ---------------------------------------------------------------------------
// Prepass: convert x + 4 weights to bf16. 1D grid: [0,8192) -> x,
// then 4 x 512 blocks for Wq,Wk,Wv,Wo. 2048 elems per block.
// ---------------------------------------------------------------------------
__global__ __launch_bounds__(256) void cvt_kernel(
    const void* __restrict__ x,  bf16* __restrict__ xb,
    const void* __restrict__ w0, const void* __restrict__ w1,
    const void* __restrict__ w2, const void* __restrict__ w3,
    bf16* __restrict__ wb, const int* __restrict__ flag)
{
    const int isf = *flag;
    const int bid = blockIdx.x;
    const void* src;
    bf16* dst;
    size_t off;
    if (bid < 8192) {
        src = x; dst = xb; off = (size_t)bid * 2048;
    } else {
        const int seg = (bid - 8192) >> 9;
        src = seg == 0 ? w0 : (seg == 1 ? w1 : (seg == 2 ? w2 : w3));
        dst = wb + (size_t)seg * W_ELEMS;
        off = (size_t)((bid - 8192) & 511) * 2048;
    }
    const size_t e = off + (size_t)threadIdx.x * 8;
    if (isf) {
        const float* gp = (const float*)src + e;
        *(bf16x8*)(dst + e) = cvt8(*(const f32x4*)gp, *(const f32x4*)(gp + 4));
    } else {
        *(u32x4*)(dst + e) = *(const u32x4*)((const bf16*)src + e);
    }
}

// async 16B global->LDS: lane i lands at (wave-uniform l) + i*16
__device__ __forceinline__ void gload_lds16(const bf16* g, bf16* l) {
    __builtin_amdgcn_global_load_lds(
        (const __attribute__((address_space(1))) void*)g,
        (__attribute__((address_space(3))) void*)l, 16, 0, 0);
}

// ---------------------------------------------------------------------------
// Kernel 1: fused QKV projection (bf16 in, bf16 out), m97 DMA staging.
// ---------------------------------------------------------------------------
__global__ __launch_bounds__(256) void qkv_kernel(
    const bf16* __restrict__ xb, const bf16* __restrict__ wb,
    const void* __restrict__ bq, const void* __restrict__ bk,
    const void* __restrict__ bv,
    bf16* __restrict__ qo, bf16* __restrict__ ko, bf16* __restrict__ vo,
    const int* __restrict__ flag)
{
    __shared__ __align__(16) bf16 As[128 * 64];
    __shared__ __align__(16) bf16 Bs[128 * 64];

    const int isf = *flag;
    const int which = blockIdx.z;
    const bf16* W   = wb + (size_t)which * W_ELEMS;
    const void* bia = which == 0 ? bq : (which == 1 ? bk : bv);
    bf16* dst       = which == 0 ? qo : (which == 1 ? ko : vo);

    const int m0 = blockIdx.x * 128;
    const int c0 = blockIdx.y * 128;
    const int tid = threadIdx.x;
    const int w = tid >> 6, lane = tid & 63;
    const int wr = w >> 1, wc = w & 1;
    const int lr = lane & 15, quad = lane >> 4;
    const int srow = (lane >> 3), scol = (lane & 7) * 8;

    f32x4 acc[4][4] = {};

    for (int kt = 0; kt < 16; ++kt) {
        const int k0 = kt * 64;
#pragma unroll
        for (int i = 0; i < 4; ++i) {
            const int chunk = i * 4 + w;                // wave-uniform
            const int row = chunk * 8 + srow;
            gload_lds16(xb + (size_t)(m0 + row) * C_DIM + k0 + scol, As + chunk * 512);
            gload_lds16(W  + (size_t)(c0 + row) * C_DIM + k0 + scol, Bs + chunk * 512);
        }
        __syncthreads();
#pragma unroll
        for (int ks = 0; ks < 2; ++ks) {
            bf16x8 af[4], bfr[4];
#pragma unroll
            for (int mi = 0; mi < 4; ++mi)
                af[mi] = *(const bf16x8*)(As + (wr * 64 + mi * 16 + lr) * 64 + ks * 32 + quad * 8);
#pragma unroll
            for (int ni = 0; ni < 4; ++ni)
                bfr[ni] = *(const bf16x8*)(Bs + (wc * 64 + ni * 16 + lr) * 64 + ks * 32 + quad * 8);
#pragma unroll
            for (int mi = 0; mi < 4; ++mi)
#pragma unroll
                for (int ni = 0; ni < 4; ++ni)
                    acc[mi][ni] = MFMA16(af[mi], bfr[ni], acc[mi][ni]);
        }
        __syncthreads();
    }

#pragma unroll
    for (int ni = 0; ni < 4; ++ni) {
        const int c = c0 + wc * 64 + ni * 16 + lr;
        const float bv_ = rd1(bia, c, isf);
#pragma unroll
        for (int mi = 0; mi < 4; ++mi) {
#pragma unroll
            for (int r = 0; r < 4; ++r) {
                const int m = m0 + wr * 64 + mi * 16 + quad * 4 + r;
                dst[(size_t)m * C_DIM + c] = (bf16)(acc[mi][ni][r] + bv_);
            }
        }
    }
}

// ---------------------------------------------------------------------------
// Kernel 2: block-sparse attention via MFMA. One wg per (nblk, bh).
// Qs[64x64], Ks[192x64]; Ps(64x192) overlays Ks after phase 1; Vt[64xVT_LD].
// qb/ob alias (in-place) -> no __restrict__ on them.
// ---------------------------------------------------------------------------
__global__ __launch_bounds__(256) void attn_kernel(
    const bf16* qb, const bf16* __restrict__ kb,
    const bf16* __restrict__ vb, bf16* ob)
{
    __shared__ __align__(16) bf16 sh[16384 + 64 * VT_LD];
    bf16* Qs = sh;               // 64x64
    bf16* Ks = sh + 4096;        // 192x64
    bf16* Ps = sh + 4096;        // 64x192, overlays Ks after phase 1
    bf16* Vt = sh + 16384;       // 64 x VT_LD (V transposed)

    const int nblk = blockIdx.x, bh = blockIdx.y, tid = threadIdx.x;
    const int b = bh >> 4, h = bh & 15;
    const int w = tid >> 6, lane = tid & 63;
    const int lr = lane & 15, quad = lane >> 4;
    const int grow = b * N_TOK + nblk * BS;
    const int colbase = h * HD;

    // ---- stage Q (64x64 slice of flat [16384,1024]) ----
#pragma unroll
    for (int p = 0; p < 2; ++p) {
        const int e = (p * 256 + tid) * 8;
        const int row = e >> 6, col = e & 63;
        *(u32x4*)(Qs + e) =
            *(const u32x4*)(qb + (size_t)(grow + row) * C_DIM + colbase + col);
    }
    // ---- stage K window (3 blocks; zero-fill out-of-range) ----
    for (int wbk = 0; wbk < 3; ++wbk) {
        const int gb = nblk - 1 + wbk;
        const bool ok = (gb >= 0 && gb < NB);
#pragma unroll
        for (int p = 0; p < 2; ++p) {
            const int e = (p * 256 + tid) * 8;
            const int row = e >> 6, col = e & 63;
            if (ok) {
                *(u32x4*)(Ks + wbk * 4096 + e) =
                    *(const u32x4*)(kb + (size_t)(b * N_TOK + gb * BS + row) * C_DIM + colbase + col);
            } else {
                u32x4 z = {};
                *(u32x4*)(Ks + wbk * 4096 + e) = z;
            }
        }
    }
    // ---- stage V transposed: Vt[dd][kwin] = V[kwin][dd] ----
    for (int t = 0; t < 48; ++t) {
        const int e = t * 256 + tid;          // 0..12287
        const int kk = e >> 6, dd = e & 63;
        const int gb = nblk - 1 + (kk >> 6);
        bf16 val = (bf16)0.f;
        if (gb >= 0 && gb < NB)
            val = vb[(size_t)(b * N_TOK + gb * BS + (kk & 63)) * C_DIM + colbase + dd];
        Vt[dd * VT_LD + kk] = val;
    }
    __syncthreads();

    // ---- phase 1: S = Q K^T ; wave w owns q-rows w*16..+15 ----
    f32x4 s[12];
    bf16x8 aq[2];
#pragma unroll
    for (int ks = 0; ks < 2; ++ks)
        aq[ks] = *(const bf16x8*)(Qs + (w * 16 + lr) * 64 + ks * 32 + quad * 8);
#pragma unroll
    for (int jt = 0; jt < 12; ++jt) {
        f32x4 a = {};
#pragma unroll
        for (int ks = 0; ks < 2; ++ks) {
            bf16x8 bk_ = *(const bf16x8*)(Ks + (jt * 16 + lr) * 64 + ks * 32 + quad * 8);
            a = MFMA16(aq[ks], bk_, a);
        }
        s[jt] = a;
    }

    // ---- mask + softmax; C-layout: row = quad*4+r, col = jt*16+lr ----
#pragma unroll
    for (int r = 0; r < 4; ++r) {
        const int i = w * 16 + quad * 4 + r;     // query row in block
        float m_ = -1e30f;
#pragma unroll
        for (int jt = 0; jt < 12; ++jt) {
            const int j = jt * 16 + lr;
            bool valid = (64 + i) >= j;
            if (j < 64 && nblk == 0) valid = false;
            if (j >= 128 && nblk == NB - 1) valid = false;
            const float sv = valid ? s[jt][r] * 0.125f : -1e30f;
            s[jt][r] = sv;
            m_ = fmaxf(m_, sv);
        }
#pragma unroll
        for (int st = 1; st < 16; st <<= 1)
            m_ = fmaxf(m_, __shfl_xor(m_, st, 64));
        float l_ = 0.f;
#pragma unroll
        for (int jt = 0; jt < 12; ++jt) {
            const float p = (s[jt][r] > -1e29f) ? __expf(s[jt][r] - m_) : 0.f;
            s[jt][r] = p;
            l_ += p;
        }
#pragma unroll
        for (int st = 1; st < 16; st <<= 1)
            l_ += __shfl_xor(l_, st, 64);
        const float inv = 1.f / l_;              // diagonal always valid
#pragma unroll
        for (int jt = 0; jt < 12; ++jt) s[jt][r] *= inv;
    }

    __syncthreads();   // everyone done reading Ks before Ps overlays it
#pragma unroll
    for (int r = 0; r < 4; ++r)
#pragma unroll
        for (int jt = 0; jt < 12; ++jt)
            Ps[(w * 16 + quad * 4 + r) * 192 + jt * 16 + lr] = (bf16)s[jt][r];
    __syncthreads();

    // ---- phase 2: O = P V  (B = V^T rows = dd) ----
    f32x4 o[4] = {};
#pragma unroll
    for (int kt = 0; kt < 6; ++kt) {
        bf16x8 ap = *(const bf16x8*)(Ps + (w * 16 + lr) * 192 + kt * 32 + quad * 8);
#pragma unroll
        for (int nt = 0; nt < 4; ++nt) {
            bf16x8 bv_ = *(const bf16x8*)(Vt + (nt * 16 + lr) * VT_LD + kt * 32 + quad * 8);
            o[nt] = MFMA16(ap, bv_, o[nt]);
        }
    }
#pragma unroll
    for (int nt = 0; nt < 4; ++nt) {
        const int dd = nt * 16 + lr;
#pragma unroll
        for (int r = 0; r < 4; ++r) {
            const int i = w * 16 + quad * 4 + r;
            ob[(size_t)(grow + i) * C_DIM + colbase + dd] = (bf16)o[nt][r];
        }
    }
}

// ---------------------------------------------------------------------------
// Kernel 3: output projection (bf16 A/W, f32 out), m97 DMA staging.
// ---------------------------------------------------------------------------
__global__ __launch_bounds__(256) void outproj_kernel(
    const bf16* __restrict__ o, const bf16* __restrict__ Wob,
    const void* __restrict__ bo, float* __restrict__ out,
    const int* __restrict__ flag)
{
    __shared__ __align__(16) bf16 As[128 * 64];
    __shared__ __align__(16) bf16 Bs[128 * 64];

    const int isf = *flag;
    const int m0 = blockIdx.x * 128;
    const int c0 = blockIdx.y * 128;
    const int tid = threadIdx.x;
    const int w = tid >> 6, lane = tid & 63;
    const int wr = w >> 1, wc = w & 1;
    const int lr = lane & 15, quad = lane >> 4;
    const int srow = (lane >> 3), scol = (lane & 7) * 8;

    f32x4 acc[4][4] = {};

    for (int kt = 0; kt < 16; ++kt) {
        const int k0 = kt * 64;
#pragma unroll
        for (int i = 0; i < 4; ++i) {
            const int chunk = i * 4 + w;
            const int row = chunk * 8 + srow;
            gload_lds16(o   + (size_t)(m0 + row) * C_DIM + k0 + scol, As + chunk * 512);
            gload_lds16(Wob + (size_t)(c0 + row) * C_DIM + k0 + scol, Bs + chunk * 512);
        }
        __syncthreads();
#pragma unroll
        for (int ks = 0; ks < 2; ++ks) {
            bf16x8 af[4], bfr[4];
#pragma unroll
            for (int mi = 0; mi < 4; ++mi)
                af[mi] = *(const bf16x8*)(As + (wr * 64 + mi * 16 + lr) * 64 + ks * 32 + quad * 8);
#pragma unroll
            for (int ni = 0; ni < 4; ++ni)
                bfr[ni] = *(const bf16x8*)(Bs + (wc * 64 + ni * 16 + lr) * 64 + ks * 32 + quad * 8);
#pragma unroll
            for (int mi = 0; mi < 4; ++mi)
#pragma unroll
                for (int ni = 0; ni < 4; ++ni)
                    acc[mi][ni] = MFMA16(af[mi], bfr[ni], acc[mi][ni]);
        }
        __syncthreads();
    }

#pragma unroll
    for (int ni = 0; ni < 4; ++ni) {
        const int c = c0 + wc * 64 + ni * 16 + lr;
        const float bv_ = rd1(bo, c, isf);
#pragma unroll
        for (int mi = 0; mi < 4; ++mi) {
#pragma unroll
            for (int r = 0; r < 4; ++r) {
                const int m = m0 + wr * 64 + mi * 16 + quad * 4 + r;
                out[(size_t)m * C_DIM + c] = acc[mi][ni][r] + bv_;
            }
        }
    }
}

extern "C" void kernel_launch(void* const* d_in, const int* in_sizes, int n_in,
                              void* d_out, int out_size, void* d_ws, size_t ws_size,
                              hipStream_t stream) {
    const void* x  = d_in[0];
    const void* Wq = d_in[1];
    const void* bq = d_in[2];
    const void* Wk = d_in[3];
    const void* bk = d_in[4];
    const void* Wv = d_in[5];
    const void* bv = d_in[6];
    const void* Wo = d_in[7];
    const void* bo = d_in[8];
    float* out = (float*)d_out;

    const int sb = (out_size + 255) / 256;
    const bool sizes_ok = (n_in == 9) &&
        in_sizes[0] == (int)QKV_ELEMS &&
        in_sizes[1] == W_ELEMS && in_sizes[2] == C_DIM &&
        in_sizes[3] == W_ELEMS && in_sizes[4] == C_DIM &&
        in_sizes[5] == W_ELEMS && in_sizes[6] == C_DIM &&
        in_sizes[7] == W_ELEMS && in_sizes[8] == C_DIM &&
        out_size == (int)QKV_ELEMS;
    if (!sizes_ok) {
        sentinel_kernel<<<sb, 256, 0, stream>>>(out, 777.0f, out_size);
        return;
    }
    // ws: flag(4KB) | q(32MB) | k(32MB) | Wb(8MB)  = 72MB + 4KB
    const size_t need = 4096 + 2 * QKV_ELEMS * sizeof(bf16) + 4 * W_ELEMS * sizeof(bf16);
    if (ws_size < need) {
        sentinel_kernel<<<sb, 256, 0, stream>>>(out, 999.0f, out_size);
        return;
    }

    int* flag = (int*)d_ws;
    bf16* q  = (bf16*)((char*)d_ws + 4096);     // attn O in-place later
    bf16* k  = q + QKV_ELEMS;
    bf16* Wb = k + QKV_ELEMS;                   // Wq|Wk|Wv|Wo bf16
    // d_out (64MB f32) parking: xb in lower 32MB, v in upper 32MB; both dead
    // before outproj's f32 stores land (same-stream kernel ordering).
    bf16* xb = (bf16*)d_out;
    bf16* v  = (bf16*)((char*)d_out + QKV_ELEMS * sizeof(bf16));

    detect_kernel<<<1, 64, 0, stream>>>((const unsigned int*)x, flag);

    cvt_kernel<<<8192 + 4 * 512, 256, 0, stream>>>(x, xb, Wq, Wk, Wv, Wo, Wb, flag);

    dim3 g1(M_TOT / 128, C_DIM / 128, 3);
    qkv_kernel<<<g1, 256, 0, stream>>>(xb, Wb, bq, bk, bv, q, k, v, flag);

    attn_kernel<<<dim3(NB, BATCH * HEADS), 256, 0, stream>>>(q, k, v, q);

    dim3 g3(M_TOT / 128, C_DIM / 128);
    outproj_kernel<<<g3, 256, 0, stream>>>(q, Wb + 3 * (size_t)W_ELEMS, bo, out, flag);
}